// Round 7
// baseline (357.614 us; speedup 1.0000x reference)
//
#include <hip/hip_runtime.h>
#include <stdint.h>

typedef unsigned short u16;
typedef __attribute__((ext_vector_type(4))) float f32x4;
typedef __attribute__((ext_vector_type(16))) float f32x16;
typedef __attribute__((ext_vector_type(8))) __bf16 bf16x8;
typedef __attribute__((ext_vector_type(4))) u16 u16x4;
typedef __attribute__((ext_vector_type(8))) u16 u16x8;
typedef __attribute__((ext_vector_type(4))) unsigned int u32x4;

#define S_LEN 2048
#define HIDDEN 4096
#define NHEAD 32
#define NKVH 8
#define HD 128
#define WIN 1024

__device__ __forceinline__ float bf2f(u16 u) {
  union { unsigned int i; float f; } x; x.i = ((unsigned int)u) << 16; return x.f;
}
__device__ __forceinline__ u16 f2bf(float f) {
  union { float f; unsigned int i; } x; x.f = f;
  unsigned int r = x.i + 0x7FFFu + ((x.i >> 16) & 1u);
  return (u16)(r >> 16);
}

__device__ __forceinline__ void gload16(const void* g, void* l) {
  __builtin_amdgcn_global_load_lds((const __attribute__((address_space(1))) void*)g,
                                   (__attribute__((address_space(3))) void*)l, 16, 0, 0);
}

__device__ __forceinline__ unsigned int cvtpk_bf16(float a, float b) {
  unsigned int w;
  asm("v_cvt_pk_bf16_f32 %0, %1, %2" : "=v"(w) : "v"(a), "v"(b));
  return w;
}

// ---------------- fp32 -> bf16 convert (X) ----------------
__global__ __launch_bounds__(256) void conv_bf16_k(const float* __restrict__ in, u16* __restrict__ out) {
  size_t i = ((size_t)blockIdx.x * 256 + threadIdx.x) * 8;
  f32x4 a = *(const f32x4*)(in + i);
  f32x4 b = *(const f32x4*)(in + i + 4);
  u16x8 o;
  o[0] = f2bf(a[0]); o[1] = f2bf(a[1]); o[2] = f2bf(a[2]); o[3] = f2bf(a[3]);
  o[4] = f2bf(b[0]); o[5] = f2bf(b[1]); o[6] = f2bf(b[2]); o[7] = f2bf(b[3]);
  *(u16x8*)(out + i) = o;
}

// ---------------- bias concat ----------------
__global__ __launch_bounds__(256) void concat_bias_k(const float* __restrict__ bq, const float* __restrict__ bk,
                                                     const float* __restrict__ bv, float* __restrict__ o) {
  int i = blockIdx.x * 256 + threadIdx.x;
  float v = (i < 4096) ? bq[i] : (i < 5120 ? bk[i - 4096] : bv[i - 5120]);
  o[i] = v;
}

// ---------------- transpose (+convert) to bf16: out[c][r] = in[r][c] ----------------
template <typename TIN>
__global__ __launch_bounds__(256) void transpose_bf16_k(const TIN* __restrict__ in, int istride,
                                                        u16* __restrict__ out, int ostride) {
  __shared__ TIN tile[64][68];
  int r0 = blockIdx.x * 64, c0 = blockIdx.y * 64;
  int t = threadIdx.x;
  int tr = t >> 4;
  int tc = (t & 15) * 4;
#pragma unroll
  for (int i = 0; i < 4; ++i) {
    int r = i * 16 + tr;
    const TIN* src = in + (size_t)(r0 + r) * istride + c0 + tc;
    if constexpr (sizeof(TIN) == 4) {
      *(f32x4*)&tile[r][tc] = *(const f32x4*)src;
    } else {
      *(u16x4*)&tile[r][tc] = *(const u16x4*)src;
    }
  }
  __syncthreads();
#pragma unroll
  for (int i = 0; i < 4; ++i) {
    int rr = i * 16 + tr;
    u16x4 o;
#pragma unroll
    for (int j = 0; j < 4; ++j) {
      if constexpr (sizeof(TIN) == 4) o[j] = f2bf((float)tile[tc + j][rr]);
      else o[j] = (u16)tile[tc + j][rr];
    }
    *(u16x4*)(out + (size_t)(c0 + rr) * ostride + r0 + tc) = o;
  }
}

// ---------------- Pipelined GEMM v3: C[M][N] = A[M][K](bf16) * Bt[N][K](bf16)^T + bias ----------------
// BM x BN tile, BK=32, 512 threads (8 waves 2Mx4N), wave-out (BM/2)x64 -> 0.375-0.5 ds_read/MFMA.
// Ring-3 LDS, tile t+2 staged during tile t, counted vmcnt(NL) per K-tile (never 0 in-loop).
// Two sub-phases per K-tile, each: {ds_reads | stage half | s_barrier | setprio 16*(MRA/8? ) MFMA}.
// 2-bit XOR chunk swizzle (chunk ^= row&3): b128 reads land exactly 8 words/bank (conflict-free).
template <int BM, int BN, int MINW, typename TOUT>
__global__ __launch_bounds__(512, MINW) void gemm3_k(const u16* __restrict__ A, const u16* __restrict__ Bt,
                                                     const float* __restrict__ bias, TOUT* __restrict__ C,
                                                     int M, int N, int K) {
  constexpr int WM = BM / 2;          // wave rows (wave grid 2Mx4N, WN=64)
  constexpr int MRA = WM / 16;        // A frags per wave per K-tile
  constexpr int NL = (BM + BN) / 128; // gload16 per thread per K-tile
  __shared__ __align__(16) u16 SA[3 * BM * 32];
  __shared__ __align__(16) u16 SB[3 * BN * 32];

  int tid = threadIdx.x;
  int w = tid >> 6, l = tid & 63;
  int cl = l & 15, g = l >> 4;
  int wr = w >> 2, wc = w & 3;

  int cpx = gridDim.x >> 3;  // XCD-bijective swizzle (grid % 8 == 0)
  int wg = (blockIdx.x & 7) * cpx + (blockIdx.x >> 3);
  int nbm = M / BM;
  int bm = wg % nbm, bn = wg / nbm;

  const u16* Ag = A + (size_t)(bm * BM) * K;
  const u16* Bg = Bt + (size_t)(bn * BN) * K;
  int srow = w * 16 + (l >> 2);                  // staging row within a 128-row half
  int csrc = ((l & 3) ^ ((l >> 2) & 3)) * 8;     // inverse-swizzled global k-chunk (elems)
  int rsw = cl & 3;                              // read swizzle bits (= row&3 for frag rows)

  f32x4 acc[MRA][4] = {};
  int NT = K >> 5;

  auto stage = [&](int slot, int tt, int h) {
    if (h < BM / 128) {
      gload16(Ag + (size_t)(h * 128 + srow) * K + tt * 32 + csrc,
              (void*)(SA + slot * (BM * 32) + h * 4096 + w * 512));
    } else {
      int hb = h - BM / 128;
      gload16(Bg + (size_t)(hb * 128 + srow) * K + tt * 32 + csrc,
              (void*)(SB + slot * (BN * 32) + hb * 4096 + w * 512));
    }
  };

  // prologue: stage tiles 0 and 1
#pragma unroll
  for (int h = 0; h < NL; ++h) stage(0, 0, h);
#pragma unroll
  for (int h = 0; h < NL; ++h) stage(1, 1, h);

  for (int t = 0; t < NT; ++t) {
    // tile t's NL loads done; tile t+1's NL stay in flight (counted, never 0)
    if constexpr (NL == 4) asm volatile("s_waitcnt vmcnt(4)" ::: "memory");
    else asm volatile("s_waitcnt vmcnt(3)" ::: "memory");
    __builtin_amdgcn_s_barrier();
    asm volatile("" ::: "memory");

    int slot = t % 3, ss = (t + 2) % 3;
    int ts = t + 2; if (ts >= NT) ts -= NT;  // dummy wrap keeps vmcnt accounting uniform
    const u16* sa = SA + slot * (BM * 32);
    const u16* sb = SB + slot * (BN * 32);

    // ---- sub-phase 0: A frags (reused all K-tile) + B ni 0,1 ----
    bf16x8 af[MRA], b0, b1;
#pragma unroll
    for (int mi = 0; mi < MRA; ++mi)
      af[mi] = *(const bf16x8*)(sa + (wr * WM + mi * 16 + cl) * 32 + ((g ^ rsw) << 3));
    b0 = *(const bf16x8*)(sb + (wc * 64 + 0 * 16 + cl) * 32 + ((g ^ rsw) << 3));
    b1 = *(const bf16x8*)(sb + (wc * 64 + 1 * 16 + cl) * 32 + ((g ^ rsw) << 3));
#pragma unroll
    for (int h = 0; h < (NL + 1) / 2; ++h) stage(ss, ts, h);
    __builtin_amdgcn_s_barrier();
    asm volatile("" ::: "memory");
    __builtin_amdgcn_s_setprio(1);
#pragma unroll
    for (int mi = 0; mi < MRA; ++mi) {
      acc[mi][0] = __builtin_amdgcn_mfma_f32_16x16x32_bf16(af[mi], b0, acc[mi][0], 0, 0, 0);
      acc[mi][1] = __builtin_amdgcn_mfma_f32_16x16x32_bf16(af[mi], b1, acc[mi][1], 0, 0, 0);
    }
    __builtin_amdgcn_s_setprio(0);
    __builtin_amdgcn_s_barrier();
    asm volatile("" ::: "memory");

    // ---- sub-phase 1: B ni 2,3 ----
    b0 = *(const bf16x8*)(sb + (wc * 64 + 2 * 16 + cl) * 32 + ((g ^ rsw) << 3));
    b1 = *(const bf16x8*)(sb + (wc * 64 + 3 * 16 + cl) * 32 + ((g ^ rsw) << 3));
#pragma unroll
    for (int h = (NL + 1) / 2; h < NL; ++h) stage(ss, ts, h);
    __builtin_amdgcn_s_barrier();
    asm volatile("" ::: "memory");
    __builtin_amdgcn_s_setprio(1);
#pragma unroll
    for (int mi = 0; mi < MRA; ++mi) {
      acc[mi][2] = __builtin_amdgcn_mfma_f32_16x16x32_bf16(af[mi], b0, acc[mi][2], 0, 0, 0);
      acc[mi][3] = __builtin_amdgcn_mfma_f32_16x16x32_bf16(af[mi], b1, acc[mi][3], 0, 0, 0);
    }
    __builtin_amdgcn_s_setprio(0);
    // loop-top vmcnt+barrier closes this K-tile
  }

  asm volatile("s_waitcnt vmcnt(0)" ::: "memory");  // drain trailing dummy stages

#pragma unroll
  for (int mi = 0; mi < MRA; ++mi) {
    int row0 = bm * BM + wr * WM + mi * 16 + g * 4;
#pragma unroll
    for (int ni = 0; ni < 4; ++ni) {
      int col = bn * BN + wc * 64 + ni * 16 + cl;
      float bb = bias[col];
      f32x4 a = acc[mi][ni];
#pragma unroll
      for (int r = 0; r < 4; ++r) {
        float v = a[r] + bb;
        if constexpr (sizeof(TOUT) == 2) C[(size_t)(row0 + r) * N + col] = f2bf(v);
        else C[(size_t)(row0 + r) * N + col] = v;
      }
    }
  }
}

// ---------------- RoPE + scatter Q (linear) / K (MFMA-fragment-packed) ----------------
// K elem (kh, s, d) -> Kf[((kh*64 + s/32)*8 + d/16)*512 + ((s&31) + 32*((d>>3)&1))*8 + (d&7)]
__global__ __launch_bounds__(256) void rope_scatter_k(const u16* __restrict__ qkv, const int* __restrict__ pos,
                                                      const float* __restrict__ cosT, const float* __restrict__ sinT,
                                                      u16* __restrict__ Q, u16* __restrict__ Kf) {
  int p = blockIdx.x * 256 + threadIdx.x;
  int s = p / 2560;
  int rem = p - s * 2560;
  int hs = rem >> 6;
  int d = rem & 63;
  int ps = pos[s];
  const float* cb = cosT + (size_t)ps * 128;
  const float* sb = sinT + (size_t)ps * 128;
  float c0 = cb[d], c1 = cb[d + 64], s0 = sb[d], s1 = sb[d + 64];
  if (hs < NHEAD) {
    const u16* src = qkv + (size_t)s * 6144 + hs * 128;
    float x0 = bf2f(src[d]), x1 = bf2f(src[d + 64]);
    const float qs = 0.08838834764831845f;  // 1/sqrt(128)
    u16* dst = Q + ((size_t)hs * S_LEN + s) * HD;
    dst[d] = f2bf((x0 * c0 - x1 * s0) * qs);
    dst[d + 64] = f2bf((x1 * c1 + x0 * s1) * qs);
  } else {
    int kh = hs - NHEAD;
    const u16* src = qkv + (size_t)s * 6144 + 4096 + kh * 128;
    float x0 = bf2f(src[d]), x1 = bf2f(src[d + 64]);
    int t = s >> 5, cr = s & 31;
    int ks = d >> 4, hi2 = (d >> 3) & 1, j = d & 7;
    size_t base = ((size_t)(kh * 64 + t) * 8 + ks) * 512 + (size_t)(cr + 32 * hi2) * 8 + j;
    Kf[base] = f2bf(x0 * c0 - x1 * s0);
    Kf[base + 4 * 512] = f2bf(x1 * c1 + x0 * s1);
  }
}

// ---------------- V -> MFMA-fragment-packed layout ----------------
// Vf chunk (kh, t, dt, sl): lane l elem j = V[t*32 + sl*16 + (l>>5)*8 + j][dt*32 + (l&31)]
__global__ __launch_bounds__(256) void vfrag_k(const u16* __restrict__ qkv, u16* __restrict__ Vf) {
  __shared__ u16 tile[32][136];  // 272B rows keep 16B vector stores aligned
  int bid = blockIdx.x;
  int kh = bid >> 6, t = bid & 63;
  int tid = threadIdx.x;
#pragma unroll
  for (int i = 0; i < 2; ++i) {
    int c = tid + i * 256;
    int r = c >> 4, seg = c & 15;
    *(u16x8*)&tile[r][seg * 8] =
        *(const u16x8*)(qkv + (size_t)(t * 32 + r) * 6144 + 5120 + kh * 128 + seg * 8);
  }
  __syncthreads();
#pragma unroll
  for (int i = 0; i < 2; ++i) {
    int pos = tid + i * 256;
    int dt = pos >> 7, sl = (pos >> 6) & 1, l = pos & 63;
    int c2 = l & 31, h2 = l >> 5;
    u16x8 o;
#pragma unroll
    for (int j = 0; j < 8; ++j) o[j] = tile[sl * 16 + h2 * 8 + j][dt * 32 + c2];
    *(u16x8*)(Vf + ((size_t)(kh * 512 + t * 8 + dt * 2 + sl)) * 512 + (size_t)l * 8) = o;
  }
}

// ---------------- flash attention: swapped-QK^T 32x32, in-register softmax ----------------
__global__ __launch_bounds__(256, 2) void attn_k(const u16* __restrict__ Q, const u16* __restrict__ Kf,
                                                 const u16* __restrict__ Vf, u16* __restrict__ O) {
  int l = threadIdx.x & 63, w = threadIdx.x >> 6;
  int col = l & 31, hi = l >> 5;
  int bid = blockIdx.x;
  int kh = bid & 7;
  int rest = bid >> 3;
  int h = kh * 4 + (rest & 3);
  int q0 = (rest >> 2) * 128 + w * 32;

  bf16x8 qf[8];
  const u16* qbase = Q + ((size_t)h * S_LEN + q0 + col) * HD + hi * 8;
#pragma unroll
  for (int ks = 0; ks < 8; ++ks) qf[ks] = *(const bf16x8*)(qbase + ks * 16);

  f32x16 ot[4];
#pragma unroll
  for (int dt = 0; dt < 4; ++dt)
#pragma unroll
    for (int r = 0; r < 16; ++r) ot[dt][r] = 0.f;
  float m_r = -3.0e38f, l_r = 0.f;

  const u16* kf0 = Kf + (size_t)kh * 64 * 4096 + (size_t)l * 8;
  const u16* vf0 = Vf + (size_t)kh * 512 * 512 + (size_t)l * 8;

  int jstart = q0 >= WIN ? q0 - WIN : 0;
  for (int j0 = jstart; j0 <= q0; j0 += 32) {
    int t = j0 >> 5;
    const u16* kb = kf0 + (size_t)t * 4096;
    bf16x8 kfr[8];
#pragma unroll
    for (int ks = 0; ks < 8; ++ks) kfr[ks] = *(const bf16x8*)(kb + ks * 512);
    f32x16 s = {};
#pragma unroll
    for (int ks = 0; ks < 8; ++ks)
      s = __builtin_amdgcn_mfma_f32_32x32x16_bf16(kfr[ks], qf[ks], s, 0, 0, 0);
    const u16* vb = vf0 + (size_t)t * 4096;
    bf16x8 vfr[8];
#pragma unroll
    for (int c = 0; c < 8; ++c) vfr[c] = *(const bf16x8*)(vb + c * 512);

    if (j0 + 31 > q0 || j0 < q0 - 992) {
      int q = q0 + col;
#pragma unroll
      for (int r = 0; r < 16; ++r) {
        int kv = j0 + (r & 3) + 8 * (r >> 2) + 4 * hi;
        if (kv > q || kv <= q - WIN) s[r] = -3.0e38f;
      }
    }
    float vm = fmaxf(fmaxf(fmaxf(s[0], s[1]), fmaxf(s[2], s[3])),
                     fmaxf(fmaxf(s[4], s[5]), fmaxf(s[6], s[7])));
    vm = fmaxf(vm, fmaxf(fmaxf(fmaxf(s[8], s[9]), fmaxf(s[10], s[11])),
                         fmaxf(fmaxf(s[12], s[13]), fmaxf(s[14], s[15]))));
    vm = fmaxf(vm, __shfl_xor(vm, 32));
    float mnew = fmaxf(m_r, vm);
    float sc = __expf(m_r - mnew);
    m_r = mnew;
    float rs = 0.f;
#pragma unroll
    for (int r = 0; r < 16; ++r) {
      float pv = __expf(s[r] - mnew);
      s[r] = pv;
      rs += pv;
    }
    rs += __shfl_xor(rs, 32);
    l_r = l_r * sc + rs;
#pragma unroll
    for (int dt = 0; dt < 4; ++dt)
#pragma unroll
      for (int r = 0; r < 16; ++r) ot[dt][r] *= sc;

    bf16x8 pb[2];
#pragma unroll
    for (int sl = 0; sl < 2; ++sl) {
      int b = sl * 8;
      unsigned int a0 = cvtpk_bf16(s[b + 0], s[b + 1]);
      unsigned int c0 = cvtpk_bf16(s[b + 4], s[b + 5]);
      asm("v_permlane32_swap_b32 %0, %1" : "+v"(a0), "+v"(c0));
      unsigned int a1 = cvtpk_bf16(s[b + 2], s[b + 3]);
      unsigned int c1 = cvtpk_bf16(s[b + 6], s[b + 7]);
      asm("v_permlane32_swap_b32 %0, %1" : "+v"(a1), "+v"(c1));
      u32x4 pv = {a0, a1, c0, c1};
      pb[sl] = __builtin_bit_cast(bf16x8, pv);
    }
#pragma unroll
    for (int dt = 0; dt < 4; ++dt) {
      ot[dt] = __builtin_amdgcn_mfma_f32_32x32x16_bf16(vfr[dt * 2 + 0], pb[0], ot[dt], 0, 0, 0);
      ot[dt] = __builtin_amdgcn_mfma_f32_32x32x16_bf16(vfr[dt * 2 + 1], pb[1], ot[dt], 0, 0, 0);
    }
  }

  float inv = 1.0f / l_r;
#pragma unroll
  for (int dt = 0; dt < 4; ++dt) {
#pragma unroll
    for (int g2 = 0; g2 < 4; ++g2) {
      u16x4 o;
#pragma unroll
      for (int i = 0; i < 4; ++i) o[i] = f2bf(ot[dt][g2 * 4 + i] * inv);
      *(u16x4*)(O + (size_t)(q0 + col) * HIDDEN + h * HD + dt * 32 + g2 * 8 + hi * 4) = o;
    }
  }
}

extern "C" void kernel_launch(void* const* d_in, const int* in_sizes, int n_in,
                              void* d_out, int out_size, void* d_ws, size_t ws_size,
                              hipStream_t stream) {
  const float* X = (const float*)d_in[0];
  const int* pos = (const int*)d_in[2];
  const float* cosT = (const float*)d_in[3];
  const float* sinT = (const float*)d_in[4];
  const float* Wq = (const float*)d_in[5];
  const float* bq = (const float*)d_in[6];
  const float* Wk = (const float*)d_in[7];
  const float* bk = (const float*)d_in[8];
  const float* Wv = (const float*)d_in[9];
  const float* bv = (const float*)d_in[10];
  const float* Wo = (const float*)d_in[11];
  const float* bo = (const float*)d_in[12];
  float* out = (float*)d_out;

  const size_t MB = 1ull << 20;
  char* ws = (char*)d_ws;
  u16* WT = (u16*)ws;                     // 48MB: Wqkv^T bf16; later Wo^T
  u16* Xb = (u16*)(ws + 48 * MB);         // 16MB: X bf16; later Q [32][2048][128]
  u16* Qs = Xb;
  u16* QKVr = (u16*)(ws + 64 * MB);       // 24MB: QKV raw [2048][6144]; later attnO [2048][4096]
  u16* attnO = QKVr;
  u16* Kfr = (u16*)(ws + 88 * MB);        // 4MB: K fragment-packed
  u16* Vfr = (u16*)(ws + 92 * MB);        // 4MB: V fragment-packed
  float* bqkv = (float*)(ws + 96 * MB);   // 24KB

  conv_bf16_k<<<4096, 256, 0, stream>>>(X, Xb);
  transpose_bf16_k<float><<<dim3(64, 64), 256, 0, stream>>>(Wq, 4096, WT, 4096);
  transpose_bf16_k<float><<<dim3(64, 16), 256, 0, stream>>>(Wk, 1024, WT + (size_t)4096 * 4096, 4096);
  transpose_bf16_k<float><<<dim3(64, 16), 256, 0, stream>>>(Wv, 1024, WT + (size_t)5120 * 4096, 4096);
  concat_bias_k<<<24, 256, 0, stream>>>(bq, bk, bv, bqkv);

  // QKV: 256x256 tiles, wave-out 128x64 -> 8 x 24 = 192 WGs
  gemm3_k<256, 256, 2, u16><<<192, 512, 0, stream>>>(Xb, WT, bqkv, QKVr, 2048, 6144, 4096);

  rope_scatter_k<<<20480, 256, 0, stream>>>(QKVr, pos, cosT, sinT, Qs, Kfr);
  vfrag_k<<<512, 256, 0, stream>>>(QKVr, Vfr);
  transpose_bf16_k<float><<<dim3(64, 64), 256, 0, stream>>>(Wo, 4096, WT, 4096);

  attn_k<<<512, 256, 0, stream>>>(Qs, Kfr, Vfr, attnO);

  // out-proj: 128x256 tiles, wave-out 64x64 -> 16 x 16 = 256 WGs, 2 blocks/CU
  gemm3_k<128, 256, 4, float><<<256, 512, 0, stream>>>(attnO, WT, bo, out, 2048, 4096, 4096);
}

// Round 8
// 348.443 us; speedup vs baseline: 1.0263x; 1.0263x over previous
//
#include <hip/hip_runtime.h>
#include <stdint.h>

typedef unsigned short u16;
typedef __attribute__((ext_vector_type(4))) float f32x4;
typedef __attribute__((ext_vector_type(16))) float f32x16;
typedef __attribute__((ext_vector_type(8))) __bf16 bf16x8;
typedef __attribute__((ext_vector_type(4))) u16 u16x4;
typedef __attribute__((ext_vector_type(8))) u16 u16x8;
typedef __attribute__((ext_vector_type(4))) unsigned int u32x4;

#define S_LEN 2048
#define HIDDEN 4096
#define NHEAD 32
#define NKVH 8
#define HD 128
#define WIN 1024

__device__ __forceinline__ float bf2f(u16 u) {
  union { unsigned int i; float f; } x; x.i = ((unsigned int)u) << 16; return x.f;
}
__device__ __forceinline__ u16 f2bf(float f) {
  union { float f; unsigned int i; } x; x.f = f;
  unsigned int r = x.i + 0x7FFFu + ((x.i >> 16) & 1u);
  return (u16)(r >> 16);
}

__device__ __forceinline__ void gload16(const void* g, void* l) {
  __builtin_amdgcn_global_load_lds((const __attribute__((address_space(1))) void*)g,
                                   (__attribute__((address_space(3))) void*)l, 16, 0, 0);
}

__device__ __forceinline__ unsigned int cvtpk_bf16(float a, float b) {
  unsigned int w;
  asm("v_cvt_pk_bf16_f32 %0, %1, %2" : "=v"(w) : "v"(a), "v"(b));
  return w;
}

// ---------------- fp32 -> bf16 convert (X) ----------------
__global__ __launch_bounds__(256) void conv_bf16_k(const float* __restrict__ in, u16* __restrict__ out) {
  size_t i = ((size_t)blockIdx.x * 256 + threadIdx.x) * 8;
  f32x4 a = *(const f32x4*)(in + i);
  f32x4 b = *(const f32x4*)(in + i + 4);
  u16x8 o;
  o[0] = f2bf(a[0]); o[1] = f2bf(a[1]); o[2] = f2bf(a[2]); o[3] = f2bf(a[3]);
  o[4] = f2bf(b[0]); o[5] = f2bf(b[1]); o[6] = f2bf(b[2]); o[7] = f2bf(b[3]);
  *(u16x8*)(out + i) = o;
}

// ---------------- bias concat ----------------
__global__ __launch_bounds__(256) void concat_bias_k(const float* __restrict__ bq, const float* __restrict__ bk,
                                                     const float* __restrict__ bv, float* __restrict__ o) {
  int i = blockIdx.x * 256 + threadIdx.x;
  float v = (i < 4096) ? bq[i] : (i < 5120 ? bk[i - 4096] : bv[i - 5120]);
  o[i] = v;
}

// ---------------- transpose (+convert) to bf16: out[c][r] = in[r][c] ----------------
template <typename TIN>
__global__ __launch_bounds__(256) void transpose_bf16_k(const TIN* __restrict__ in, int istride,
                                                        u16* __restrict__ out, int ostride) {
  __shared__ TIN tile[64][68];
  int r0 = blockIdx.x * 64, c0 = blockIdx.y * 64;
  int t = threadIdx.x;
  int tr = t >> 4;
  int tc = (t & 15) * 4;
#pragma unroll
  for (int i = 0; i < 4; ++i) {
    int r = i * 16 + tr;
    const TIN* src = in + (size_t)(r0 + r) * istride + c0 + tc;
    if constexpr (sizeof(TIN) == 4) {
      *(f32x4*)&tile[r][tc] = *(const f32x4*)src;
    } else {
      *(u16x4*)&tile[r][tc] = *(const u16x4*)src;
    }
  }
  __syncthreads();
#pragma unroll
  for (int i = 0; i < 4; ++i) {
    int rr = i * 16 + tr;
    u16x4 o;
#pragma unroll
    for (int j = 0; j < 4; ++j) {
      if constexpr (sizeof(TIN) == 4) o[j] = f2bf((float)tile[tc + j][rr]);
      else o[j] = (u16)tile[tc + j][rr];
    }
    *(u16x4*)(out + (size_t)(c0 + rr) * ostride + r0 + tc) = o;
  }
}

// ---------------- Pipelined GEMM v4: 4-wave blocks, >=2 blocks/CU ----------------
// C[M][N] = A[M][K](bf16) * Bt[N][K](bf16)^T + bias.  BK=32, 256 threads (4 waves, 2x2),
// wave-out (BM/2)x(BN/2). Ring-3 LDS; all of tile t+2 staged at top of tile t (2-tile slack);
// counted vmcnt(NL) per K-tile (never 0 in-loop). Cross-block overlap (2 blocks/CU) hides
// the per-block barrier drain (m114 mechanism). XOR chunk swizzle chunk^=(row>>1)&3
// (inverse-swizzled global source, forward on ds_read) -> measured-0-conflict pattern.
template <int BM, int BN, int MINW, typename TOUT>
__global__ __launch_bounds__(256, MINW) void gemm4_k(const u16* __restrict__ A, const u16* __restrict__ Bt,
                                                     const float* __restrict__ bias, TOUT* __restrict__ C,
                                                     int M, int N, int K) {
  constexpr int WM = BM / 2, WN = BN / 2;
  constexpr int MRA = WM / 16, MRB = WN / 16;
  constexpr int NA = BM / 64, NB = BN / 64;
  constexpr int NL = NA + NB;              // gload16 per thread per K-tile (64-row units)
  __shared__ __align__(16) u16 SA[3 * BM * 32];
  __shared__ __align__(16) u16 SB[3 * BN * 32];

  int tid = threadIdx.x;
  int w = tid >> 6, l = tid & 63;
  int cl = l & 15, g = l >> 4;
  int wr = w >> 1, wc = w & 1;

  int cpx = gridDim.x >> 3;  // XCD-bijective swizzle (grid % 8 == 0)
  int wg = (blockIdx.x & 7) * cpx + (blockIdx.x >> 3);
  int nbm = M / BM;
  int bm = wg % nbm, bn = wg / nbm;

  const u16* Ag = A + (size_t)(bm * BM) * K;
  const u16* Bg = Bt + (size_t)(bn * BN) * K;
  int srow = w * 16 + (l >> 2);                  // staging row within a 64-row unit
  int csrc = ((l & 3) ^ ((l >> 3) & 3)) * 8;     // inverse-swizzled global k-chunk
  int rdc = (g ^ ((cl >> 1) & 3)) << 3;          // forward swizzle on fragment ds_read

  f32x4 acc[MRA][MRB] = {};
  int NT = K >> 5;

  auto stage = [&](int slot, int tt, int h) {
    if (h < NA) {
      gload16(Ag + (size_t)(h * 64 + srow) * K + tt * 32 + csrc,
              (void*)(SA + slot * (BM * 32) + (h * 64 + w * 16) * 32));
    } else {
      int hb = h - NA;
      gload16(Bg + (size_t)(hb * 64 + srow) * K + tt * 32 + csrc,
              (void*)(SB + slot * (BN * 32) + (hb * 64 + w * 16) * 32));
    }
  };

  // prologue: stage tiles 0 and 1
#pragma unroll
  for (int h = 0; h < NL; ++h) stage(0, 0, h);
#pragma unroll
  for (int h = 0; h < NL; ++h) stage(1, 1, h);

  for (int t = 0; t < NT; ++t) {
    // tile t's NL loads complete (tile t+1's NL stay in flight; never drain to 0 in-loop)
    if constexpr (NL == 5) asm volatile("s_waitcnt vmcnt(5)" ::: "memory");
    else asm volatile("s_waitcnt vmcnt(4)" ::: "memory");
    __builtin_amdgcn_s_barrier();
    asm volatile("" ::: "memory");

    int slot = t % 3, ss = (t + 2) % 3;
    int ts = t + 2; if (ts >= NT) ts -= NT;  // dummy wrap keeps vmcnt accounting uniform
#pragma unroll
    for (int h = 0; h < NL; ++h) stage(ss, ts, h);

    const u16* sa = SA + slot * (BM * 32);
    const u16* sb = SB + slot * (BN * 32);
    bf16x8 af[MRA], bf[MRB];
#pragma unroll
    for (int mi = 0; mi < MRA; ++mi)
      af[mi] = *(const bf16x8*)(sa + (wr * WM + mi * 16 + cl) * 32 + rdc);
#pragma unroll
    for (int ni = 0; ni < MRB; ++ni)
      bf[ni] = *(const bf16x8*)(sb + (wc * WN + ni * 16 + cl) * 32 + rdc);
    __builtin_amdgcn_s_setprio(1);
#pragma unroll
    for (int mi = 0; mi < MRA; ++mi)
#pragma unroll
      for (int ni = 0; ni < MRB; ++ni)
        acc[mi][ni] = __builtin_amdgcn_mfma_f32_16x16x32_bf16(af[mi], bf[ni], acc[mi][ni], 0, 0, 0);
    __builtin_amdgcn_s_setprio(0);
  }

  asm volatile("s_waitcnt vmcnt(0)" ::: "memory");  // drain trailing dummy stages

#pragma unroll
  for (int mi = 0; mi < MRA; ++mi) {
    int row0 = bm * BM + wr * WM + mi * 16 + g * 4;
#pragma unroll
    for (int ni = 0; ni < MRB; ++ni) {
      int col = bn * BN + wc * WN + ni * 16 + cl;
      float bb = bias[col];
      f32x4 a = acc[mi][ni];
#pragma unroll
      for (int r = 0; r < 4; ++r) {
        float v = a[r] + bb;
        if constexpr (sizeof(TOUT) == 2) C[(size_t)(row0 + r) * N + col] = f2bf(v);
        else C[(size_t)(row0 + r) * N + col] = v;
      }
    }
  }
}

// ---------------- RoPE + scatter Q (linear) / K (MFMA-fragment-packed) ----------------
// K elem (kh, s, d) -> Kf[((kh*64 + s/32)*8 + d/16)*512 + ((s&31) + 32*((d>>3)&1))*8 + (d&7)]
__global__ __launch_bounds__(256) void rope_scatter_k(const u16* __restrict__ qkv, const int* __restrict__ pos,
                                                      const float* __restrict__ cosT, const float* __restrict__ sinT,
                                                      u16* __restrict__ Q, u16* __restrict__ Kf) {
  int p = blockIdx.x * 256 + threadIdx.x;
  int s = p / 2560;
  int rem = p - s * 2560;
  int hs = rem >> 6;
  int d = rem & 63;
  int ps = pos[s];
  const float* cb = cosT + (size_t)ps * 128;
  const float* sb = sinT + (size_t)ps * 128;
  float c0 = cb[d], c1 = cb[d + 64], s0 = sb[d], s1 = sb[d + 64];
  if (hs < NHEAD) {
    const u16* src = qkv + (size_t)s * 6144 + hs * 128;
    float x0 = bf2f(src[d]), x1 = bf2f(src[d + 64]);
    const float qs = 0.08838834764831845f;  // 1/sqrt(128)
    u16* dst = Q + ((size_t)hs * S_LEN + s) * HD;
    dst[d] = f2bf((x0 * c0 - x1 * s0) * qs);
    dst[d + 64] = f2bf((x1 * c1 + x0 * s1) * qs);
  } else {
    int kh = hs - NHEAD;
    const u16* src = qkv + (size_t)s * 6144 + 4096 + kh * 128;
    float x0 = bf2f(src[d]), x1 = bf2f(src[d + 64]);
    int t = s >> 5, cr = s & 31;
    int ks = d >> 4, hi2 = (d >> 3) & 1, j = d & 7;
    size_t base = ((size_t)(kh * 64 + t) * 8 + ks) * 512 + (size_t)(cr + 32 * hi2) * 8 + j;
    Kf[base] = f2bf(x0 * c0 - x1 * s0);
    Kf[base + 4 * 512] = f2bf(x1 * c1 + x0 * s1);
  }
}

// ---------------- V -> MFMA-fragment-packed layout ----------------
// Vf chunk (kh, t, dt, sl): lane l elem j = V[t*32 + sl*16 + (l>>5)*8 + j][dt*32 + (l&31)]
__global__ __launch_bounds__(256) void vfrag_k(const u16* __restrict__ qkv, u16* __restrict__ Vf) {
  __shared__ u16 tile[32][136];  // 272B rows keep 16B vector stores aligned
  int bid = blockIdx.x;
  int kh = bid >> 6, t = bid & 63;
  int tid = threadIdx.x;
#pragma unroll
  for (int i = 0; i < 2; ++i) {
    int c = tid + i * 256;
    int r = c >> 4, seg = c & 15;
    *(u16x8*)&tile[r][seg * 8] =
        *(const u16x8*)(qkv + (size_t)(t * 32 + r) * 6144 + 5120 + kh * 128 + seg * 8);
  }
  __syncthreads();
#pragma unroll
  for (int i = 0; i < 2; ++i) {
    int pos = tid + i * 256;
    int dt = pos >> 7, sl = (pos >> 6) & 1, l = pos & 63;
    int c2 = l & 31, h2 = l >> 5;
    u16x8 o;
#pragma unroll
    for (int j = 0; j < 8; ++j) o[j] = tile[sl * 16 + h2 * 8 + j][dt * 32 + c2];
    *(u16x8*)(Vf + ((size_t)(kh * 512 + t * 8 + dt * 2 + sl)) * 512 + (size_t)l * 8) = o;
  }
}

// ---------------- flash attention: swapped-QK^T 32x32, in-register softmax ----------------
__global__ __launch_bounds__(256, 2) void attn_k(const u16* __restrict__ Q, const u16* __restrict__ Kf,
                                                 const u16* __restrict__ Vf, u16* __restrict__ O) {
  int l = threadIdx.x & 63, w = threadIdx.x >> 6;
  int col = l & 31, hi = l >> 5;
  int bid = blockIdx.x;
  int kh = bid & 7;
  int rest = bid >> 3;
  int h = kh * 4 + (rest & 3);
  int q0 = (rest >> 2) * 128 + w * 32;

  bf16x8 qf[8];
  const u16* qbase = Q + ((size_t)h * S_LEN + q0 + col) * HD + hi * 8;
#pragma unroll
  for (int ks = 0; ks < 8; ++ks) qf[ks] = *(const bf16x8*)(qbase + ks * 16);

  f32x16 ot[4];
#pragma unroll
  for (int dt = 0; dt < 4; ++dt)
#pragma unroll
    for (int r = 0; r < 16; ++r) ot[dt][r] = 0.f;
  float m_r = -3.0e38f, l_r = 0.f;

  const u16* kf0 = Kf + (size_t)kh * 64 * 4096 + (size_t)l * 8;
  const u16* vf0 = Vf + (size_t)kh * 512 * 512 + (size_t)l * 8;

  int jstart = q0 >= WIN ? q0 - WIN : 0;
  for (int j0 = jstart; j0 <= q0; j0 += 32) {
    int t = j0 >> 5;
    const u16* kb = kf0 + (size_t)t * 4096;
    bf16x8 kfr[8];
#pragma unroll
    for (int ks = 0; ks < 8; ++ks) kfr[ks] = *(const bf16x8*)(kb + ks * 512);
    f32x16 s = {};
#pragma unroll
    for (int ks = 0; ks < 8; ++ks)
      s = __builtin_amdgcn_mfma_f32_32x32x16_bf16(kfr[ks], qf[ks], s, 0, 0, 0);
    const u16* vb = vf0 + (size_t)t * 4096;
    bf16x8 vfr[8];
#pragma unroll
    for (int c = 0; c < 8; ++c) vfr[c] = *(const bf16x8*)(vb + c * 512);

    if (j0 + 31 > q0 || j0 < q0 - 992) {
      int q = q0 + col;
#pragma unroll
      for (int r = 0; r < 16; ++r) {
        int kv = j0 + (r & 3) + 8 * (r >> 2) + 4 * hi;
        if (kv > q || kv <= q - WIN) s[r] = -3.0e38f;
      }
    }
    float vm = fmaxf(fmaxf(fmaxf(s[0], s[1]), fmaxf(s[2], s[3])),
                     fmaxf(fmaxf(s[4], s[5]), fmaxf(s[6], s[7])));
    vm = fmaxf(vm, fmaxf(fmaxf(fmaxf(s[8], s[9]), fmaxf(s[10], s[11])),
                         fmaxf(fmaxf(s[12], s[13]), fmaxf(s[14], s[15]))));
    vm = fmaxf(vm, __shfl_xor(vm, 32));
    float mnew = fmaxf(m_r, vm);
    float sc = __expf(m_r - mnew);
    m_r = mnew;
    float rs = 0.f;
#pragma unroll
    for (int r = 0; r < 16; ++r) {
      float pv = __expf(s[r] - mnew);
      s[r] = pv;
      rs += pv;
    }
    rs += __shfl_xor(rs, 32);
    l_r = l_r * sc + rs;
#pragma unroll
    for (int dt = 0; dt < 4; ++dt)
#pragma unroll
      for (int r = 0; r < 16; ++r) ot[dt][r] *= sc;

    bf16x8 pb[2];
#pragma unroll
    for (int sl = 0; sl < 2; ++sl) {
      int b = sl * 8;
      unsigned int a0 = cvtpk_bf16(s[b + 0], s[b + 1]);
      unsigned int c0 = cvtpk_bf16(s[b + 4], s[b + 5]);
      asm("v_permlane32_swap_b32 %0, %1" : "+v"(a0), "+v"(c0));
      unsigned int a1 = cvtpk_bf16(s[b + 2], s[b + 3]);
      unsigned int c1 = cvtpk_bf16(s[b + 6], s[b + 7]);
      asm("v_permlane32_swap_b32 %0, %1" : "+v"(a1), "+v"(c1));
      u32x4 pv = {a0, a1, c0, c1};
      pb[sl] = __builtin_bit_cast(bf16x8, pv);
    }
#pragma unroll
    for (int dt = 0; dt < 4; ++dt) {
      ot[dt] = __builtin_amdgcn_mfma_f32_32x32x16_bf16(vfr[dt * 2 + 0], pb[0], ot[dt], 0, 0, 0);
      ot[dt] = __builtin_amdgcn_mfma_f32_32x32x16_bf16(vfr[dt * 2 + 1], pb[1], ot[dt], 0, 0, 0);
    }
  }

  float inv = 1.0f / l_r;
#pragma unroll
  for (int dt = 0; dt < 4; ++dt) {
#pragma unroll
    for (int g2 = 0; g2 < 4; ++g2) {
      u16x4 o;
#pragma unroll
      for (int i = 0; i < 4; ++i) o[i] = f2bf(ot[dt][g2 * 4 + i] * inv);
      *(u16x4*)(O + (size_t)(q0 + col) * HIDDEN + h * HD + dt * 32 + g2 * 8 + hi * 4) = o;
    }
  }
}

extern "C" void kernel_launch(void* const* d_in, const int* in_sizes, int n_in,
                              void* d_out, int out_size, void* d_ws, size_t ws_size,
                              hipStream_t stream) {
  const float* X = (const float*)d_in[0];
  const int* pos = (const int*)d_in[2];
  const float* cosT = (const float*)d_in[3];
  const float* sinT = (const float*)d_in[4];
  const float* Wq = (const float*)d_in[5];
  const float* bq = (const float*)d_in[6];
  const float* Wk = (const float*)d_in[7];
  const float* bk = (const float*)d_in[8];
  const float* Wv = (const float*)d_in[9];
  const float* bv = (const float*)d_in[10];
  const float* Wo = (const float*)d_in[11];
  const float* bo = (const float*)d_in[12];
  float* out = (float*)d_out;

  const size_t MB = 1ull << 20;
  char* ws = (char*)d_ws;
  u16* WT = (u16*)ws;                     // 48MB: Wqkv^T bf16; later Wo^T
  u16* Xb = (u16*)(ws + 48 * MB);         // 16MB: X bf16; later Q [32][2048][128]
  u16* Qs = Xb;
  u16* QKVr = (u16*)(ws + 64 * MB);       // 24MB: QKV raw [2048][6144]; later attnO [2048][4096]
  u16* attnO = QKVr;
  u16* Kfr = (u16*)(ws + 88 * MB);        // 4MB: K fragment-packed
  u16* Vfr = (u16*)(ws + 92 * MB);        // 4MB: V fragment-packed
  float* bqkv = (float*)(ws + 96 * MB);   // 24KB

  conv_bf16_k<<<4096, 256, 0, stream>>>(X, Xb);
  transpose_bf16_k<float><<<dim3(64, 64), 256, 0, stream>>>(Wq, 4096, WT, 4096);
  transpose_bf16_k<float><<<dim3(64, 16), 256, 0, stream>>>(Wk, 1024, WT + (size_t)4096 * 4096, 4096);
  transpose_bf16_k<float><<<dim3(64, 16), 256, 0, stream>>>(Wv, 1024, WT + (size_t)5120 * 4096, 4096);
  concat_bias_k<<<24, 256, 0, stream>>>(bq, bk, bv, bqkv);

  // QKV: 128x192 tiles, 4 waves (wave-out 64x96), 60KB LDS -> 2 blocks/CU, 16x32=512 WGs (exactly 2/CU)
  gemm4_k<128, 192, 2, u16><<<512, 256, 0, stream>>>(Xb, WT, bqkv, QKVr, 2048, 6144, 4096);

  rope_scatter_k<<<20480, 256, 0, stream>>>(QKVr, pos, cosT, sinT, Qs, Kfr);
  vfrag_k<<<512, 256, 0, stream>>>(QKVr, Vfr);
  transpose_bf16_k<float><<<dim3(64, 64), 256, 0, stream>>>(Wo, 4096, WT, 4096);

  attn_k<<<512, 256, 0, stream>>>(Qs, Kfr, Vfr, attnO);

  // out-proj: 128x128 tiles, 4 waves (wave-out 64x64), 48KB LDS, 16x32=512 WGs (2/CU)
  gemm4_k<128, 128, 2, float><<<512, 256, 0, stream>>>(attnO, WT, bo, out, 2048, 4096, 4096);
}

// Round 9
// 340.229 us; speedup vs baseline: 1.0511x; 1.0241x over previous
//
#include <hip/hip_runtime.h>
#include <stdint.h>

typedef unsigned short u16;
typedef __attribute__((ext_vector_type(4))) float f32x4;
typedef __attribute__((ext_vector_type(16))) float f32x16;
typedef __attribute__((ext_vector_type(8))) __bf16 bf16x8;
typedef __attribute__((ext_vector_type(4))) u16 u16x4;
typedef __attribute__((ext_vector_type(8))) u16 u16x8;
typedef __attribute__((ext_vector_type(4))) unsigned int u32x4;

#define S_LEN 2048
#define HIDDEN 4096
#define NHEAD 32
#define NKVH 8
#define HD 128
#define WIN 1024

__device__ __forceinline__ float bf2f(u16 u) {
  union { unsigned int i; float f; } x; x.i = ((unsigned int)u) << 16; return x.f;
}
__device__ __forceinline__ u16 f2bf(float f) {
  union { float f; unsigned int i; } x; x.f = f;
  unsigned int r = x.i + 0x7FFFu + ((x.i >> 16) & 1u);
  return (u16)(r >> 16);
}

__device__ __forceinline__ void gload16(const void* g, void* l) {
  __builtin_amdgcn_global_load_lds((const __attribute__((address_space(1))) void*)g,
                                   (__attribute__((address_space(3))) void*)l, 16, 0, 0);
}

__device__ __forceinline__ unsigned int cvtpk_bf16(float a, float b) {
  unsigned int w;
  asm("v_cvt_pk_bf16_f32 %0, %1, %2" : "=v"(w) : "v"(a), "v"(b));
  return w;
}

// ---------------- fp32 -> bf16 convert (X) ----------------
__global__ __launch_bounds__(256) void conv_bf16_k(const float* __restrict__ in, u16* __restrict__ out) {
  size_t i = ((size_t)blockIdx.x * 256 + threadIdx.x) * 8;
  f32x4 a = *(const f32x4*)(in + i);
  f32x4 b = *(const f32x4*)(in + i + 4);
  u16x8 o;
  o[0] = f2bf(a[0]); o[1] = f2bf(a[1]); o[2] = f2bf(a[2]); o[3] = f2bf(a[3]);
  o[4] = f2bf(b[0]); o[5] = f2bf(b[1]); o[6] = f2bf(b[2]); o[7] = f2bf(b[3]);
  *(u16x8*)(out + i) = o;
}

// ---------------- bias concat ----------------
__global__ __launch_bounds__(256) void concat_bias_k(const float* __restrict__ bq, const float* __restrict__ bk,
                                                     const float* __restrict__ bv, float* __restrict__ o) {
  int i = blockIdx.x * 256 + threadIdx.x;
  float v = (i < 4096) ? bq[i] : (i < 5120 ? bk[i - 4096] : bv[i - 5120]);
  o[i] = v;
}

// ---------------- transpose (+convert) to bf16: out[c][r] = in[r][c] ----------------
template <typename TIN>
__global__ __launch_bounds__(256) void transpose_bf16_k(const TIN* __restrict__ in, int istride,
                                                        u16* __restrict__ out, int ostride) {
  __shared__ TIN tile[64][68];
  int r0 = blockIdx.x * 64, c0 = blockIdx.y * 64;
  int t = threadIdx.x;
  int tr = t >> 4;
  int tc = (t & 15) * 4;
#pragma unroll
  for (int i = 0; i < 4; ++i) {
    int r = i * 16 + tr;
    const TIN* src = in + (size_t)(r0 + r) * istride + c0 + tc;
    if constexpr (sizeof(TIN) == 4) {
      *(f32x4*)&tile[r][tc] = *(const f32x4*)src;
    } else {
      *(u16x4*)&tile[r][tc] = *(const u16x4*)src;
    }
  }
  __syncthreads();
#pragma unroll
  for (int i = 0; i < 4; ++i) {
    int rr = i * 16 + tr;
    u16x4 o;
#pragma unroll
    for (int j = 0; j < 4; ++j) {
      if constexpr (sizeof(TIN) == 4) o[j] = f2bf((float)tile[tc + j][rr]);
      else o[j] = (u16)tile[tc + j][rr];
    }
    *(u16x4*)(out + (size_t)(c0 + rr) * ostride + r0 + tc) = o;
  }
}

// ---------------- Pipelined GEMM v4: 4-wave blocks, 3 blocks/CU ----------------
// C[M][N] = A[M][K](bf16) * Bt[N][K](bf16)^T + bias.  BK=32, 256 threads (4 waves, 2x2),
// wave-out (BM/2)x(BN/2). Ring-3 LDS; all of tile t+2 staged at top of tile t (2-tile slack);
// counted vmcnt(NL) per K-tile (never 0 in-loop). Cross-block overlap (3 blocks/CU = 12
// waves/CU, the m97/m114 sweet spot) hides the per-block barrier drain.
// XOR chunk swizzle chunk^=(row>>1)&3 (inverse on global source, forward on ds_read) -> 0 conflicts.
template <int BM, int BN, int MINW, typename TOUT>
__global__ __launch_bounds__(256, MINW) void gemm4_k(const u16* __restrict__ A, const u16* __restrict__ Bt,
                                                     const float* __restrict__ bias, TOUT* __restrict__ C,
                                                     int M, int N, int K) {
  constexpr int WM = BM / 2, WN = BN / 2;
  constexpr int MRA = WM / 16, MRB = WN / 16;
  constexpr int NA = BM / 64, NB = BN / 64;
  constexpr int NL = NA + NB;              // gload16 per thread per K-tile (64-row units)
  __shared__ __align__(16) u16 SA[3 * BM * 32];
  __shared__ __align__(16) u16 SB[3 * BN * 32];

  int tid = threadIdx.x;
  int w = tid >> 6, l = tid & 63;
  int cl = l & 15, g = l >> 4;
  int wr = w >> 1, wc = w & 1;

  int cpx = gridDim.x >> 3;  // XCD-bijective swizzle (grid % 8 == 0)
  int wg = (blockIdx.x & 7) * cpx + (blockIdx.x >> 3);
  int nbm = M / BM;
  int bm = wg % nbm, bn = wg / nbm;

  const u16* Ag = A + (size_t)(bm * BM) * K;
  const u16* Bg = Bt + (size_t)(bn * BN) * K;
  int srow = w * 16 + (l >> 2);                  // staging row within a 64-row unit
  int csrc = ((l & 3) ^ ((l >> 3) & 3)) * 8;     // inverse-swizzled global k-chunk
  int rdc = (g ^ ((cl >> 1) & 3)) << 3;          // forward swizzle on fragment ds_read

  f32x4 acc[MRA][MRB] = {};
  int NT = K >> 5;

  auto stage = [&](int slot, int tt, int h) {
    if (h < NA) {
      gload16(Ag + (size_t)(h * 64 + srow) * K + tt * 32 + csrc,
              (void*)(SA + slot * (BM * 32) + (h * 64 + w * 16) * 32));
    } else {
      int hb = h - NA;
      gload16(Bg + (size_t)(hb * 64 + srow) * K + tt * 32 + csrc,
              (void*)(SB + slot * (BN * 32) + (hb * 64 + w * 16) * 32));
    }
  };

  // prologue: stage tiles 0 and 1
#pragma unroll
  for (int h = 0; h < NL; ++h) stage(0, 0, h);
#pragma unroll
  for (int h = 0; h < NL; ++h) stage(1, 1, h);

  for (int t = 0; t < NT; ++t) {
    // tile t's NL loads complete (tile t+1's NL stay in flight; never drain to 0 in-loop)
    if constexpr (NL == 5) asm volatile("s_waitcnt vmcnt(5)" ::: "memory");
    else asm volatile("s_waitcnt vmcnt(4)" ::: "memory");
    __builtin_amdgcn_s_barrier();
    asm volatile("" ::: "memory");

    int slot = t % 3, ss = (t + 2) % 3;
    int ts = t + 2; if (ts >= NT) ts -= NT;  // dummy wrap keeps vmcnt accounting uniform
#pragma unroll
    for (int h = 0; h < NL; ++h) stage(ss, ts, h);

    const u16* sa = SA + slot * (BM * 32);
    const u16* sb = SB + slot * (BN * 32);
    bf16x8 af[MRA], bf[MRB];
#pragma unroll
    for (int mi = 0; mi < MRA; ++mi)
      af[mi] = *(const bf16x8*)(sa + (wr * WM + mi * 16 + cl) * 32 + rdc);
#pragma unroll
    for (int ni = 0; ni < MRB; ++ni)
      bf[ni] = *(const bf16x8*)(sb + (wc * WN + ni * 16 + cl) * 32 + rdc);
    __builtin_amdgcn_s_setprio(1);
#pragma unroll
    for (int mi = 0; mi < MRA; ++mi)
#pragma unroll
      for (int ni = 0; ni < MRB; ++ni)
        acc[mi][ni] = __builtin_amdgcn_mfma_f32_16x16x32_bf16(af[mi], bf[ni], acc[mi][ni], 0, 0, 0);
    __builtin_amdgcn_s_setprio(0);
  }

  asm volatile("s_waitcnt vmcnt(0)" ::: "memory");  // drain trailing dummy stages

#pragma unroll
  for (int mi = 0; mi < MRA; ++mi) {
    int row0 = bm * BM + wr * WM + mi * 16 + g * 4;
#pragma unroll
    for (int ni = 0; ni < MRB; ++ni) {
      int col = bn * BN + wc * WN + ni * 16 + cl;
      float bb = bias[col];
      f32x4 a = acc[mi][ni];
#pragma unroll
      for (int r = 0; r < 4; ++r) {
        float v = a[r] + bb;
        if constexpr (sizeof(TOUT) == 2) C[(size_t)(row0 + r) * N + col] = f2bf(v);
        else C[(size_t)(row0 + r) * N + col] = v;
      }
    }
  }
}

// ---------------- RoPE + scatter Q (linear) / K (MFMA-fragment-packed) ----------------
// K elem (kh, s, d) -> Kf[((kh*64 + s/32)*8 + d/16)*512 + ((s&31) + 32*((d>>3)&1))*8 + (d&7)]
__global__ __launch_bounds__(256) void rope_scatter_k(const u16* __restrict__ qkv, const int* __restrict__ pos,
                                                      const float* __restrict__ cosT, const float* __restrict__ sinT,
                                                      u16* __restrict__ Q, u16* __restrict__ Kf) {
  int p = blockIdx.x * 256 + threadIdx.x;
  int s = p / 2560;
  int rem = p - s * 2560;
  int hs = rem >> 6;
  int d = rem & 63;
  int ps = pos[s];
  const float* cb = cosT + (size_t)ps * 128;
  const float* sb = sinT + (size_t)ps * 128;
  float c0 = cb[d], c1 = cb[d + 64], s0 = sb[d], s1 = sb[d + 64];
  if (hs < NHEAD) {
    const u16* src = qkv + (size_t)s * 6144 + hs * 128;
    float x0 = bf2f(src[d]), x1 = bf2f(src[d + 64]);
    const float qs = 0.08838834764831845f;  // 1/sqrt(128)
    u16* dst = Q + ((size_t)hs * S_LEN + s) * HD;
    dst[d] = f2bf((x0 * c0 - x1 * s0) * qs);
    dst[d + 64] = f2bf((x1 * c1 + x0 * s1) * qs);
  } else {
    int kh = hs - NHEAD;
    const u16* src = qkv + (size_t)s * 6144 + 4096 + kh * 128;
    float x0 = bf2f(src[d]), x1 = bf2f(src[d + 64]);
    int t = s >> 5, cr = s & 31;
    int ks = d >> 4, hi2 = (d >> 3) & 1, j = d & 7;
    size_t base = ((size_t)(kh * 64 + t) * 8 + ks) * 512 + (size_t)(cr + 32 * hi2) * 8 + j;
    Kf[base] = f2bf(x0 * c0 - x1 * s0);
    Kf[base + 4 * 512] = f2bf(x1 * c1 + x0 * s1);
  }
}

// ---------------- V -> MFMA-fragment-packed layout ----------------
// Vf chunk (kh, t, dt, sl): lane l elem j = V[t*32 + sl*16 + (l>>5)*8 + j][dt*32 + (l&31)]
__global__ __launch_bounds__(256) void vfrag_k(const u16* __restrict__ qkv, u16* __restrict__ Vf) {
  __shared__ u16 tile[32][136];  // 272B rows keep 16B vector stores aligned
  int bid = blockIdx.x;
  int kh = bid >> 6, t = bid & 63;
  int tid = threadIdx.x;
#pragma unroll
  for (int i = 0; i < 2; ++i) {
    int c = tid + i * 256;
    int r = c >> 4, seg = c & 15;
    *(u16x8*)&tile[r][seg * 8] =
        *(const u16x8*)(qkv + (size_t)(t * 32 + r) * 6144 + 5120 + kh * 128 + seg * 8);
  }
  __syncthreads();
#pragma unroll
  for (int i = 0; i < 2; ++i) {
    int pos = tid + i * 256;
    int dt = pos >> 7, sl = (pos >> 6) & 1, l = pos & 63;
    int c2 = l & 31, h2 = l >> 5;
    u16x8 o;
#pragma unroll
    for (int j = 0; j < 8; ++j) o[j] = tile[sl * 16 + h2 * 8 + j][dt * 32 + c2];
    *(u16x8*)(Vf + ((size_t)(kh * 512 + t * 8 + dt * 2 + sl)) * 512 + (size_t)l * 8) = o;
  }
}

// ---------------- flash attention: swapped-QK^T 32x32, in-register softmax ----------------
// qb interleave-remap balances per-CU work (KV-trip count varies 1..33 with q0);
// K-fragments double-buffered across KV tiles (L2 latency hidden under softmax+PV).
__global__ __launch_bounds__(256, 2) void attn_k(const u16* __restrict__ Q, const u16* __restrict__ Kf,
                                                 const u16* __restrict__ Vf, u16* __restrict__ O) {
  int l = threadIdx.x & 63, w = threadIdx.x >> 6;
  int col = l & 31, hi = l >> 5;
  int bid = blockIdx.x;
  int kh = bid & 7;
  int head = (bid >> 3) & 3;
  int qbp = bid >> 5;
  int qb = (qbp & 1) ? (15 - (qbp >> 1)) : (qbp >> 1);  // {0,15,1,14,...}: heavy+light pairing
  int h = kh * 4 + head;
  int q0 = qb * 128 + w * 32;

  bf16x8 qf[8];
  const u16* qbase = Q + ((size_t)h * S_LEN + q0 + col) * HD + hi * 8;
#pragma unroll
  for (int ks = 0; ks < 8; ++ks) qf[ks] = *(const bf16x8*)(qbase + ks * 16);

  f32x16 ot[4];
#pragma unroll
  for (int dt = 0; dt < 4; ++dt)
#pragma unroll
    for (int r = 0; r < 16; ++r) ot[dt][r] = 0.f;
  float m_r = -3.0e38f, l_r = 0.f;

  const u16* kf0 = Kf + (size_t)kh * 64 * 4096 + (size_t)l * 8;
  const u16* vf0 = Vf + (size_t)kh * 512 * 512 + (size_t)l * 8;

  int jstart = q0 >= WIN ? q0 - WIN : 0;
  // preload first tile's K fragments
  bf16x8 kfr[8];
  {
    const u16* kb = kf0 + (size_t)(jstart >> 5) * 4096;
#pragma unroll
    for (int ks = 0; ks < 8; ++ks) kfr[ks] = *(const bf16x8*)(kb + ks * 512);
  }

  for (int j0 = jstart; j0 <= q0; j0 += 32) {
    int t = j0 >> 5;
    // S^T = K * Q^T
    f32x16 s = {};
#pragma unroll
    for (int ks = 0; ks < 8; ++ks)
      s = __builtin_amdgcn_mfma_f32_32x32x16_bf16(kfr[ks], qf[ks], s, 0, 0, 0);
    // prefetch next tile's K fragments (hidden under softmax + PV)
    int tn = (j0 + 32 <= q0) ? (t + 1) : t;
    const u16* kbn = kf0 + (size_t)tn * 4096;
    bf16x8 kfn[8];
#pragma unroll
    for (int ks = 0; ks < 8; ++ks) kfn[ks] = *(const bf16x8*)(kbn + ks * 512);
    // V fragments for current tile
    const u16* vb = vf0 + (size_t)t * 4096;
    bf16x8 vfr[8];
#pragma unroll
    for (int c = 0; c < 8; ++c) vfr[c] = *(const bf16x8*)(vb + c * 512);

    if (j0 + 31 > q0 || j0 < q0 - 992) {
      int q = q0 + col;
#pragma unroll
      for (int r = 0; r < 16; ++r) {
        int kv = j0 + (r & 3) + 8 * (r >> 2) + 4 * hi;
        if (kv > q || kv <= q - WIN) s[r] = -3.0e38f;
      }
    }
    float vm = fmaxf(fmaxf(fmaxf(s[0], s[1]), fmaxf(s[2], s[3])),
                     fmaxf(fmaxf(s[4], s[5]), fmaxf(s[6], s[7])));
    vm = fmaxf(vm, fmaxf(fmaxf(fmaxf(s[8], s[9]), fmaxf(s[10], s[11])),
                         fmaxf(fmaxf(s[12], s[13]), fmaxf(s[14], s[15]))));
    vm = fmaxf(vm, __shfl_xor(vm, 32));
    float mnew = fmaxf(m_r, vm);
    float sc = __expf(m_r - mnew);
    m_r = mnew;
    float rs = 0.f;
#pragma unroll
    for (int r = 0; r < 16; ++r) {
      float pv = __expf(s[r] - mnew);
      s[r] = pv;
      rs += pv;
    }
    rs += __shfl_xor(rs, 32);
    l_r = l_r * sc + rs;
#pragma unroll
    for (int dt = 0; dt < 4; ++dt)
#pragma unroll
      for (int r = 0; r < 16; ++r) ot[dt][r] *= sc;

    bf16x8 pb[2];
#pragma unroll
    for (int sl = 0; sl < 2; ++sl) {
      int b = sl * 8;
      unsigned int a0 = cvtpk_bf16(s[b + 0], s[b + 1]);
      unsigned int c0 = cvtpk_bf16(s[b + 4], s[b + 5]);
      asm("v_permlane32_swap_b32 %0, %1" : "+v"(a0), "+v"(c0));
      unsigned int a1 = cvtpk_bf16(s[b + 2], s[b + 3]);
      unsigned int c1 = cvtpk_bf16(s[b + 6], s[b + 7]);
      asm("v_permlane32_swap_b32 %0, %1" : "+v"(a1), "+v"(c1));
      u32x4 pv = {a0, a1, c0, c1};
      pb[sl] = __builtin_bit_cast(bf16x8, pv);
    }
#pragma unroll
    for (int dt = 0; dt < 4; ++dt) {
      ot[dt] = __builtin_amdgcn_mfma_f32_32x32x16_bf16(vfr[dt * 2 + 0], pb[0], ot[dt], 0, 0, 0);
      ot[dt] = __builtin_amdgcn_mfma_f32_32x32x16_bf16(vfr[dt * 2 + 1], pb[1], ot[dt], 0, 0, 0);
    }
#pragma unroll
    for (int ks = 0; ks < 8; ++ks) kfr[ks] = kfn[ks];
  }

  float inv = 1.0f / l_r;
#pragma unroll
  for (int dt = 0; dt < 4; ++dt) {
#pragma unroll
    for (int g2 = 0; g2 < 4; ++g2) {
      u16x4 o;
#pragma unroll
      for (int i = 0; i < 4; ++i) o[i] = f2bf(ot[dt][g2 * 4 + i] * inv);
      *(u16x4*)(O + (size_t)(q0 + col) * HIDDEN + h * HD + dt * 32 + g2 * 8 + hi * 4) = o;
    }
  }
}

extern "C" void kernel_launch(void* const* d_in, const int* in_sizes, int n_in,
                              void* d_out, int out_size, void* d_ws, size_t ws_size,
                              hipStream_t stream) {
  const float* X = (const float*)d_in[0];
  const int* pos = (const int*)d_in[2];
  const float* cosT = (const float*)d_in[3];
  const float* sinT = (const float*)d_in[4];
  const float* Wq = (const float*)d_in[5];
  const float* bq = (const float*)d_in[6];
  const float* Wk = (const float*)d_in[7];
  const float* bk = (const float*)d_in[8];
  const float* Wv = (const float*)d_in[9];
  const float* bv = (const float*)d_in[10];
  const float* Wo = (const float*)d_in[11];
  const float* bo = (const float*)d_in[12];
  float* out = (float*)d_out;

  const size_t MB = 1ull << 20;
  char* ws = (char*)d_ws;
  u16* WT = (u16*)ws;                     // 48MB: Wqkv^T bf16; later Wo^T
  u16* Xb = (u16*)(ws + 48 * MB);         // 16MB: X bf16; later Q [32][2048][128]
  u16* Qs = Xb;
  u16* QKVr = (u16*)(ws + 64 * MB);       // 24MB: QKV raw [2048][6144]; later attnO [2048][4096]
  u16* attnO = QKVr;
  u16* Kfr = (u16*)(ws + 88 * MB);        // 4MB: K fragment-packed
  u16* Vfr = (u16*)(ws + 92 * MB);        // 4MB: V fragment-packed
  float* bqkv = (float*)(ws + 96 * MB);   // 24KB

  conv_bf16_k<<<4096, 256, 0, stream>>>(X, Xb);
  transpose_bf16_k<float><<<dim3(64, 64), 256, 0, stream>>>(Wq, 4096, WT, 4096);
  transpose_bf16_k<float><<<dim3(64, 16), 256, 0, stream>>>(Wk, 1024, WT + (size_t)4096 * 4096, 4096);
  transpose_bf16_k<float><<<dim3(64, 16), 256, 0, stream>>>(Wv, 1024, WT + (size_t)5120 * 4096, 4096);
  concat_bias_k<<<24, 256, 0, stream>>>(bq, bk, bv, bqkv);

  // QKV: 128x128 tiles, 4 waves (wave-out 64x64), 48KB LDS -> 3 blocks/CU, 16x48=768 WGs (exactly 3/CU)
  gemm4_k<128, 128, 3, u16><<<768, 256, 0, stream>>>(Xb, WT, bqkv, QKVr, 2048, 6144, 4096);

  rope_scatter_k<<<20480, 256, 0, stream>>>(QKVr, pos, cosT, sinT, Qs, Kfr);
  vfrag_k<<<512, 256, 0, stream>>>(QKVr, Vfr);
  transpose_bf16_k<float><<<dim3(64, 64), 256, 0, stream>>>(Wo, 4096, WT, 4096);

  attn_k<<<512, 256, 0, stream>>>(Qs, Kfr, Vfr, attnO);

  // out-proj: 128x128 tiles, 16x32=512 WGs, 3 blocks/CU capacity
  gemm4_k<128, 128, 3, float><<<512, 256, 0, stream>>>(attnO, WT, bo, out, 2048, 4096, 4096);
}